// Round 1
// baseline (128.994 us; speedup 1.0000x reference)
//
#include <hip/hip_runtime.h>
#include <hip/hip_bf16.h>

// InfoNCE loss, B=8, N=2048, D=256, temperature 0.1.
// ws layout (needs 32768 + 8 MiB):
//   [0]   float gsum, [4] float gcnt
//   [16]  uchar maskC[B*N]
//   [32768] ushort z[B*N*D]   (bf16-normalized embeddings)

#define B_ 8
#define N_ 2048
#define D_ 256
#define SP 264  // padded LDS row stride in bf16 elems (256+8): row stride 528B -> 2-way bank aliasing (free)

typedef __attribute__((ext_vector_type(8))) short bf16x8;
typedef __attribute__((ext_vector_type(4))) float f32x4;

__device__ __forceinline__ unsigned short f2bf(float f) {
  unsigned int u = __float_as_uint(f);
  unsigned int r = (u + 0x7fffu + ((u >> 16) & 1u)) >> 16;  // RNE
  return (unsigned short)r;
}

// Detect mask dtype (bool bytes vs int32), canonicalize to uchar, zero accumulators.
__global__ void prep_kernel(const void* maskRaw, float* gsum, unsigned char* maskC) {
  __shared__ int cnt_s;
  const int tid = threadIdx.x;
  if (tid == 0) cnt_s = 0;
  __syncthreads();
  const unsigned char* bp = (const unsigned char*)maskRaw;
  int c = 0;
  for (int i = tid; i < B_ * N_; i += 256)
    if ((i & 3) && bp[i]) c++;
  atomicAdd(&cnt_s, c);
  __syncthreads();
  const bool isInt32 = (cnt_s == 0);  // int32 0/1 values: bytes 1..3 of each elem are 0
  const int* ip = (const int*)maskRaw;
  for (int i = tid; i < B_ * N_; i += 256)
    maskC[i] = isInt32 ? (unsigned char)(ip[i] != 0) : (unsigned char)(bp[i] != 0);
  if (tid == 0) { gsum[0] = 0.f; gsum[1] = 0.f; }
}

// One wave per row: L2-normalize, write bf16.
__global__ void norm_kernel(const float* __restrict__ emb, unsigned short* __restrict__ z) {
  const int row = blockIdx.x * 4 + (threadIdx.x >> 6);
  const int l = threadIdx.x & 63;
  const float4 v = *(const float4*)(emb + (size_t)row * D_ + l * 4);
  float ss = v.x * v.x + v.y * v.y + v.z * v.z + v.w * v.w;
#pragma unroll
  for (int m = 1; m < 64; m <<= 1) ss += __shfl_xor(ss, m);
  const float inv = 1.f / fmaxf(sqrtf(ss), 1e-12f);
  ushort4 o;
  o.x = f2bf(v.x * inv);
  o.y = f2bf(v.y * inv);
  o.z = f2bf(v.z * inv);
  o.w = f2bf(v.w * inv);
  *(ushort4*)(z + (size_t)row * D_ + l * 4) = o;
}

// Block = 4 waves = 64 anchor rows; loops all 2048 columns in 64-wide LDS tiles.
// Per wave: 16 rows, A-fragments (16x256 bf16) fully in registers.
__global__ __launch_bounds__(256, 2) void main_kernel(
    const unsigned short* __restrict__ z, const int* __restrict__ groups,
    const unsigned char* __restrict__ maskC, float* gsum) {
  __shared__ unsigned short colZ[64 * SP];
  __shared__ int gjs[64];
  __shared__ float mjs[64];

  const int b = blockIdx.y;
  const int rowBase = blockIdx.x * 64;
  const int tid = threadIdx.x;
  const int w = tid >> 6;
  const int l = tid & 63;
  const int l15 = l & 15;
  const int lg = l >> 4;

  const unsigned short* zb = z + (size_t)b * N_ * D_;
  const int* gb = groups + b * N_;
  const unsigned char* mb = maskC + b * N_;

  // A fragment layout for mfma_f32_16x16x32_bf16: lane l holds row (l&15),
  // k = 8*(l>>4) + e, e=0..7 contiguous (m92-verified bf16x8 pattern).
  bf16x8 afrag[8];
  const int arow = rowBase + w * 16 + l15;
#pragma unroll
  for (int kt = 0; kt < 8; kt++)
    afrag[kt] = *(const bf16x8*)(zb + arow * D_ + kt * 32 + lg * 8);

  int irow[4], gi[4];
#pragma unroll
  for (int r = 0; r < 4; r++) {
    irow[r] = rowBase + w * 16 + lg * 4 + r;  // C/D: row = 4*(l>>4)+reg
    gi[r] = gb[irow[r]];
  }

  float dP[4] = {0.f, 0.f, 0.f, 0.f};
  float nP[4] = {0.f, 0.f, 0.f, 0.f};

  for (int ct = 0; ct < N_ / 64; ct++) {
    __syncthreads();
    // stage 64 column-rows of Z (32 KB), coalesced 16B chunks
#pragma unroll
    for (int it = 0; it < 8; it++) {
      const int chunk = it * 256 + tid;
      const int crow = chunk >> 5;
      const int cc = chunk & 31;
      bf16x8 v = *(const bf16x8*)(zb + (ct * 64 + crow) * D_ + cc * 8);
      *(bf16x8*)(&colZ[crow * SP + cc * 8]) = v;
    }
    if (tid < 64) {
      const int j = ct * 64 + tid;
      gjs[tid] = gb[j];
      mjs[tid] = mb[j] ? 1.f : 0.f;
    }
    __syncthreads();

#pragma unroll
    for (int sub = 0; sub < 4; sub++) {
      f32x4 acc = {0.f, 0.f, 0.f, 0.f};
      const unsigned short* bp = &colZ[(sub * 16 + l15) * SP + lg * 8];
#pragma unroll
      for (int kt = 0; kt < 8; kt++) {
        bf16x8 bfrag = *(const bf16x8*)(bp + kt * 32);
        acc = __builtin_amdgcn_mfma_f32_16x16x32_bf16(afrag[kt], bfrag, acc, 0, 0, 0);
      }
      const int j = ct * 64 + sub * 16 + l15;
      const int gj = gjs[sub * 16 + l15];
      const float mj = mjs[sub * 16 + l15];
#pragma unroll
      for (int r = 0; r < 4; r++) {
        float e = __expf(10.f * acc[r]) * mj;  // sim = cos/0.1
        if (j == irow[r]) e = 0.f;             // exclude diagonal
        dP[r] += e;
        nP[r] += (gj == gi[r]) ? e : 0.f;
      }
    }
  }

  // reduce over the 16-lane column axis (xor 1,2,4,8 stays within lg group)
  float contrib = 0.f, cnt = 0.f;
#pragma unroll
  for (int r = 0; r < 4; r++) {
    float d = dP[r], n = nP[r];
#pragma unroll
    for (int m = 1; m < 16; m <<= 1) {
      d += __shfl_xor(d, m);
      n += __shfl_xor(n, m);
    }
    if (l15 == 0) {
      const bool valid = (mb[irow[r]] != 0) && (n > 0.f);
      if (valid) {
        contrib += __logf(d) - __logf(n);  // -log(numer/denom)
        cnt += 1.f;
      }
    }
  }
  // sum lanes {0,16,32,48}
  contrib += __shfl_xor(contrib, 16);
  contrib += __shfl_xor(contrib, 32);
  cnt += __shfl_xor(cnt, 16);
  cnt += __shfl_xor(cnt, 32);
  if (l == 0) {
    atomicAdd(&gsum[0], contrib);
    atomicAdd(&gsum[1], cnt);
  }
}

__global__ void fin_kernel(const float* gsum, float* out) {
  const float s = gsum[0], c = gsum[1];
  out[0] = (c > 0.f) ? s / fmaxf(c, 1.f) : 0.f;
}

extern "C" void kernel_launch(void* const* d_in, const int* in_sizes, int n_in,
                              void* d_out, int out_size, void* d_ws, size_t ws_size,
                              hipStream_t stream) {
  const float* emb = (const float*)d_in[0];
  const int* groups = (const int*)d_in[1];
  const void* mask = d_in[2];
  float* out = (float*)d_out;

  char* ws = (char*)d_ws;
  float* gsum = (float*)ws;
  unsigned char* maskC = (unsigned char*)(ws + 16);
  unsigned short* z = (unsigned short*)(ws + 32768);

  prep_kernel<<<1, 256, 0, stream>>>(mask, gsum, maskC);
  norm_kernel<<<(B_ * N_) / 4, 256, 0, stream>>>(emb, z);
  main_kernel<<<dim3(N_ / 64, B_), 256, 0, stream>>>(z, groups, maskC, gsum);
  fin_kernel<<<1, 1, 0, stream>>>(gsum, out);
}

// Round 2
// 104.384 us; speedup vs baseline: 1.2358x; 1.2358x over previous
//
#include <hip/hip_runtime.h>
#include <hip/hip_bf16.h>

// InfoNCE loss, B=8, N=2048, D=256, T=0.1.
// ws layout (~1.2 MB):
//   [0]      float gsum[4]   (0: loss sum, 1: count, 2: mask-dtype flag)
//   [64]     float invn[B*N]       (64 KB)
//   [65600]  int   gm[B*N]         (64 KB)  group | (masked_out ? 0x10000 : 0)
//   [131136] float pd[B*N*NCH]     (512 KB) per-chunk denom partials
//   [655424] float pn[B*N*NCH]     (512 KB) per-chunk numer partials

#define B_ 8
#define N_ 2048
#define D_ 256
#define NCH 8      // column chunks -> grid 16x8x8 = 1024 blocks (~3 resident/CU)
#define CCOLS 256  // columns per chunk
#define BROWS 128  // rows per block = 4 waves x 32 rows

typedef __attribute__((ext_vector_type(8))) short bf16x8;
typedef __attribute__((ext_vector_type(4))) float f32x4;

__device__ __forceinline__ bf16x8 pack8(float4 a, float4 b, float s) {
  union { bf16x8 v; __hip_bfloat162 h[4]; } u;
  u.h[0] = __float22bfloat162_rn(float2{a.x * s, a.y * s});
  u.h[1] = __float22bfloat162_rn(float2{a.z * s, a.w * s});
  u.h[2] = __float22bfloat162_rn(float2{b.x * s, b.y * s});
  u.h[3] = __float22bfloat162_rn(float2{b.z * s, b.w * s});
  return u.v;
}

// Detect mask dtype (bool bytes vs int32 0/1 values) and zero accumulators.
__global__ void det_kernel(const int* __restrict__ maskRaw, float* gsum) {
  __shared__ int cnt_s;
  if (threadIdx.x == 0) cnt_s = 0;
  __syncthreads();
  const int4* p = (const int4*)maskRaw;
  int c = 0;
  for (int i = threadIdx.x; i < (B_ * N_) / 4; i += 256) {
    const int4 v = p[i];
    c += ((v.x & 0xFFFFFF00) != 0) + ((v.y & 0xFFFFFF00) != 0) +
         ((v.z & 0xFFFFFF00) != 0) + ((v.w & 0xFFFFFF00) != 0);
  }
  atomicAdd(&cnt_s, c);
  __syncthreads();
  if (threadIdx.x == 0) {
    gsum[0] = 0.f; gsum[1] = 0.f;
    gsum[2] = (cnt_s == 0) ? 1.f : 0.f;  // 1 => int32 mask
  }
}

// One wave per row: inv-norm only. Threads 0..3 also fuse mask into groups.
__global__ void norm_kernel(const float* __restrict__ emb, const void* __restrict__ maskRaw,
                            const int* __restrict__ groups, const float* __restrict__ gsum,
                            float* __restrict__ invn, int* __restrict__ gm) {
  const int w = threadIdx.x >> 6, l = threadIdx.x & 63;
  const int row = blockIdx.x * 4 + w;
  const float4 v = *(const float4*)(emb + (size_t)row * D_ + l * 4);
  float ss = v.x * v.x + v.y * v.y + v.z * v.z + v.w * v.w;
#pragma unroll
  for (int m = 1; m < 64; m <<= 1) ss += __shfl_xor(ss, m);
  if (l == 0) invn[row] = 1.f / fmaxf(sqrtf(ss), 1e-12f);
  if (threadIdx.x < 4) {
    const int i = blockIdx.x * 4 + threadIdx.x;
    const bool isInt = gsum[2] != 0.f;
    const bool mk = isInt ? (((const int*)maskRaw)[i] != 0)
                          : (((const unsigned char*)maskRaw)[i] != 0);
    gm[i] = groups[i] | (mk ? 0 : 0x10000);
  }
}

// Block: 4 waves x 32 rows = 128 rows, one 256-col chunk. Staged 64-col LDS
// tiles, XOR-swizzled (byte ^= (row&7)<<4) for conflict-free ds_read_b128.
// Each bfrag read feeds 2 MFMAs (2 row-tiles per wave).
__global__ __launch_bounds__(256, 3) void main_kernel(
    const float* __restrict__ emb, const float* __restrict__ invn,
    const int* __restrict__ gm, float* __restrict__ pd, float* __restrict__ pn) {
  __shared__ unsigned short colZ[64 * 256];
  __shared__ int gjs[64];

  const int b = blockIdx.z;
  const int rowBase = blockIdx.x * BROWS;
  const int colBase = blockIdx.y * CCOLS;
  const int tid = threadIdx.x;
  const int w = tid >> 6, l = tid & 63, l15 = l & 15, lg = l >> 4;

  const float* eb = emb + (size_t)b * N_ * D_;
  const float* nb = invn + b * N_;
  const int* gb = gm + b * N_;

  // A fragments: lane holds row (l&15) of each 16-row tile, k = 8*(l>>4)+e.
  bf16x8 afrag[2][8];
#pragma unroll
  for (int t2 = 0; t2 < 2; t2++) {
    const int row = rowBase + w * 32 + t2 * 16 + l15;
    const float s = nb[row];
#pragma unroll
    for (int kt = 0; kt < 8; kt++) {
      const float* gp = eb + (size_t)row * D_ + kt * 32 + lg * 8;
      afrag[t2][kt] = pack8(*(const float4*)gp, *(const float4*)(gp + 4), s);
    }
  }

  int gi[2][4], irow[2][4];
#pragma unroll
  for (int t2 = 0; t2 < 2; t2++)
#pragma unroll
    for (int r = 0; r < 4; r++) {
      irow[t2][r] = rowBase + w * 32 + t2 * 16 + lg * 4 + r;  // C/D row map
      gi[t2][r] = gb[irow[t2][r]];
    }

  float dP[2][4] = {{0.f, 0.f, 0.f, 0.f}, {0.f, 0.f, 0.f, 0.f}};
  float nP[2][4] = {{0.f, 0.f, 0.f, 0.f}, {0.f, 0.f, 0.f, 0.f}};

  for (int ct = 0; ct < CCOLS / 64; ct++) {
    const int colT = colBase + ct * 64;
    __syncthreads();
    // stage 64 col-rows: f32 -> *invn -> bf16 -> swizzled ds_write_b128
#pragma unroll
    for (int it = 0; it < 8; it++) {
      const int s = it * 256 + tid;
      const int r = s >> 5, c = s & 31;
      const float* gp = eb + (size_t)(colT + r) * D_ + c * 8;
      const float sc = nb[colT + r];
      *(bf16x8*)((char*)colZ + r * 512 + ((c ^ (r & 7)) * 16)) =
          pack8(*(const float4*)gp, *(const float4*)(gp + 4), sc);
    }
    if (tid < 64) gjs[tid] = gb[colT + tid];
    __syncthreads();

#pragma unroll
    for (int sub = 0; sub < 4; sub++) {
      f32x4 acc0 = {0.f, 0.f, 0.f, 0.f};
      f32x4 acc1 = {0.f, 0.f, 0.f, 0.f};
      const int brow = sub * 16 + l15;
      const char* bbase = (const char*)colZ + brow * 512;
      const int bx = (brow & 7) << 4;
#pragma unroll
      for (int kt = 0; kt < 8; kt++) {
        const bf16x8 bfrag = *(const bf16x8*)(bbase + ((lg * 16 + kt * 64) ^ bx));
        acc0 = __builtin_amdgcn_mfma_f32_16x16x32_bf16(afrag[0][kt], bfrag, acc0, 0, 0, 0);
        acc1 = __builtin_amdgcn_mfma_f32_16x16x32_bf16(afrag[1][kt], bfrag, acc1, 0, 0, 0);
      }
      const int j = colT + sub * 16 + l15;
      const int gj = gjs[sub * 16 + l15];
      const float mj = (gj & 0x10000) ? 0.f : 1.f;
#pragma unroll
      for (int r = 0; r < 4; r++) {
        float e0 = __expf(10.f * acc0[r]) * mj;  // sim = cos/0.1
        float e1 = __expf(10.f * acc1[r]) * mj;
        if (j == irow[0][r]) e0 = 0.f;  // exclude diagonal
        if (j == irow[1][r]) e1 = 0.f;
        dP[0][r] += e0;
        dP[1][r] += e1;
        if (gj == gi[0][r]) nP[0][r] += e0;
        if (gj == gi[1][r]) nP[1][r] += e1;
      }
    }
  }

  // reduce over the 16-lane column axis; lane l15==0 owns the row
#pragma unroll
  for (int t2 = 0; t2 < 2; t2++)
#pragma unroll
    for (int r = 0; r < 4; r++) {
      float d = dP[t2][r], n = nP[t2][r];
#pragma unroll
      for (int m = 1; m < 16; m <<= 1) {
        d += __shfl_xor(d, m);
        n += __shfl_xor(n, m);
      }
      if (l15 == 0) {
        const int row = rowBase + w * 32 + t2 * 16 + lg * 4 + r;
        const size_t o = ((size_t)b * N_ + row) * NCH + blockIdx.y;
        pd[o] = d;
        pn[o] = n;
      }
    }
}

__global__ void finalize_kernel(const float* __restrict__ pd, const float* __restrict__ pn,
                                const int* __restrict__ gm, float* gsum) {
  const int i = blockIdx.x * 256 + threadIdx.x;
  float d = 0.f, n = 0.f;
#pragma unroll
  for (int c = 0; c < NCH; c++) {
    d += pd[(size_t)i * NCH + c];
    n += pn[(size_t)i * NCH + c];
  }
  float contrib = 0.f, cnt = 0.f;
  if (!(gm[i] & 0x10000) && n > 0.f) {
    contrib = __logf(d) - __logf(n);  // -log(numer/denom)
    cnt = 1.f;
  }
#pragma unroll
  for (int m = 1; m < 64; m <<= 1) {
    contrib += __shfl_xor(contrib, m);
    cnt += __shfl_xor(cnt, m);
  }
  __shared__ float sc[4], sn[4];
  const int w = threadIdx.x >> 6;
  if ((threadIdx.x & 63) == 0) { sc[w] = contrib; sn[w] = cnt; }
  __syncthreads();
  if (threadIdx.x == 0) {
    atomicAdd(&gsum[0], sc[0] + sc[1] + sc[2] + sc[3]);
    atomicAdd(&gsum[1], sn[0] + sn[1] + sn[2] + sn[3]);
  }
}

__global__ void fin_kernel(const float* gsum, float* out) {
  const float s = gsum[0], c = gsum[1];
  out[0] = (c > 0.f) ? s / fmaxf(c, 1.f) : 0.f;
}

extern "C" void kernel_launch(void* const* d_in, const int* in_sizes, int n_in,
                              void* d_out, int out_size, void* d_ws, size_t ws_size,
                              hipStream_t stream) {
  const float* emb = (const float*)d_in[0];
  const int* groups = (const int*)d_in[1];
  const void* mask = d_in[2];
  float* out = (float*)d_out;

  char* ws = (char*)d_ws;
  float* gsum = (float*)ws;
  float* invn = (float*)(ws + 64);
  int* gm = (int*)(ws + 64 + 65536);
  float* pd = (float*)(ws + 131136);
  float* pn = pd + (size_t)B_ * N_ * NCH;

  det_kernel<<<1, 256, 0, stream>>>((const int*)mask, gsum);
  norm_kernel<<<(B_ * N_) / 4, 256, 0, stream>>>(emb, mask, groups, gsum, invn, gm);
  main_kernel<<<dim3(N_ / BROWS, NCH, B_), 256, 0, stream>>>(emb, invn, gm, pd, pn);
  finalize_kernel<<<(B_ * N_) / 256, 256, 0, stream>>>(pd, pn, gm, gsum);
  fin_kernel<<<1, 1, 0, stream>>>(gsum, out);
}

// Round 3
// 50.017 us; speedup vs baseline: 2.5790x; 2.0870x over previous
//
#include <hip/hip_runtime.h>
#include <hip/hip_bf16.h>

// InfoNCE loss, B=8, N=2048, D=256, T=0.1.
// ws layout (~8.6 MB):
//   [0]        float gsum[16]  (0: loss sum, 1: count, 2: mask-dtype flag)
//   [64]       int   gm[B*N]        (64 KB)  group | (masked_out ? 0x10000 : 0)
//   [65600]    ushort z[B*N*D]      (8 MB)   bf16 L2-normalized embeddings
//   [8454208]  float pd[NCH*B*N]    (256 KB) per-chunk denom partials
//   [8716352]  float pn[NCH*B*N]    (256 KB) per-chunk numer partials

#define B_ 8
#define N_ 2048
#define D_ 256
#define NCH 4      // column chunks -> grid 16x4x8 = 512 blocks = exactly 2/CU
#define CCOLS 512  // columns per chunk
#define BROWS 128  // rows per block = 4 waves x 32 rows
#define NT (CCOLS / 64)
#define NEGB -16384.0f

typedef __attribute__((ext_vector_type(8))) short bf16x8;
typedef __attribute__((ext_vector_type(4))) float f32x4;

__device__ __forceinline__ void gload16(const void* g, void* l) {
  __builtin_amdgcn_global_load_lds(
      (const __attribute__((address_space(1))) void*)g,
      (__attribute__((address_space(3))) void*)l, 16, 0, 0);
}

// Detect mask dtype (bool bytes vs int32 0/1 values); only reads the first
// 16KB (the bool-size of the buffer) to stay in bounds for either dtype.
__global__ void det_kernel(const int* __restrict__ maskRaw, float* gsum) {
  __shared__ int cnt_s;
  if (threadIdx.x == 0) cnt_s = 0;
  __syncthreads();
  const int4* p = (const int4*)maskRaw;
  int c = 0;
  for (int i = threadIdx.x; i < 1024; i += 256) {  // 1024 int4 = 16 KB
    const int4 v = p[i];
    c += ((v.x & 0xFFFFFF00) != 0) + ((v.y & 0xFFFFFF00) != 0) +
         ((v.z & 0xFFFFFF00) != 0) + ((v.w & 0xFFFFFF00) != 0);
  }
  atomicAdd(&cnt_s, c);
  __syncthreads();
  if (threadIdx.x == 0) {
    gsum[0] = 0.f; gsum[1] = 0.f;
    gsum[2] = (cnt_s == 0) ? 1.f : 0.f;  // 1 => int32 mask
  }
}

// One wave per row: L2-normalize -> bf16 z. Threads 0..3 fuse mask into groups.
__global__ void norm_kernel(const float* __restrict__ emb, const void* __restrict__ maskRaw,
                            const int* __restrict__ groups, const float* __restrict__ gsum,
                            unsigned short* __restrict__ z, int* __restrict__ gm) {
  const int w = threadIdx.x >> 6, l = threadIdx.x & 63;
  const int row = blockIdx.x * 4 + w;
  const float4 v = *(const float4*)(emb + (size_t)row * D_ + l * 4);
  float ss = v.x * v.x + v.y * v.y + v.z * v.z + v.w * v.w;
#pragma unroll
  for (int m = 1; m < 64; m <<= 1) ss += __shfl_xor(ss, m);
  const float inv = 1.f / fmaxf(sqrtf(ss), 1e-12f);
  union { ushort4 u; __hip_bfloat162 h[2]; } o;
  o.h[0] = __float22bfloat162_rn(float2{v.x * inv, v.y * inv});
  o.h[1] = __float22bfloat162_rn(float2{v.z * inv, v.w * inv});
  *(ushort4*)(z + (size_t)row * D_ + l * 4) = o.u;
  if (threadIdx.x < 4) {
    const int i = blockIdx.x * 4 + threadIdx.x;
    const bool isInt = gsum[2] != 0.f;
    const bool mk = isInt ? (((const int*)maskRaw)[i] != 0)
                          : (((const unsigned char*)maskRaw)[i] != 0);
    gm[i] = groups[i] | (mk ? 0 : 0x10000);
  }
}

// Block: 4 waves x 32 rows = 128 rows x one 512-col chunk.
// Double-buffered 64-col LDS tiles via global_load_lds (linear LDS dest,
// XOR-pre-swizzled global source; reads use the matching XOR). T3 minimal
// 2-phase: issue next-tile STAGE before computing current tile.
__global__ __launch_bounds__(256, 2) void main_kernel(
    const unsigned short* __restrict__ z, const int* __restrict__ gm,
    float* __restrict__ pd, float* __restrict__ pn) {
  __shared__ unsigned short colZ[2][64 * 256];  // 2 x 32 KB

  const int b = blockIdx.z;
  const int rowBase = blockIdx.x * BROWS;
  const int chunkBase = blockIdx.y * CCOLS;
  const int tid = threadIdx.x;
  const int w = tid >> 6, l = tid & 63, l15 = l & 15, lg = l >> 4;
  const bool hasDiag = (rowBase >> 9) == (int)blockIdx.y;

  const unsigned short* zb = z + (size_t)b * N_ * D_;
  const int* gb = gm + b * N_;

  // per-lane pre-swizzled source offset within a 32KB tile (involution:
  // LDS[L] = G[L ^ ((row&7)<<4)], row = L>>9; here (L>>9)&7 == (tid>>5)&7)
  const int srcOff = (tid * 16) ^ (((tid >> 5) & 7) << 4);
  const char* srcBase = (const char*)zb + (size_t)chunkBase * (D_ * 2) + srcOff;
  const int ldsOff = tid * 16;

  // prologue: stage tile 0
#pragma unroll
  for (int i = 0; i < 8; i++)
    gload16(srcBase + i * 4096, (char*)colZ[0] + i * 4096 + ldsOff);

  // A fragments: lane holds row (l&15), k = kt*32 + lg*8 + e
  bf16x8 afrag[2][8];
#pragma unroll
  for (int t2 = 0; t2 < 2; t2++) {
    const int arow = rowBase + w * 32 + t2 * 16 + l15;
#pragma unroll
    for (int kt = 0; kt < 8; kt++)
      afrag[t2][kt] = *(const bf16x8*)(zb + (size_t)arow * D_ + kt * 32 + lg * 8);
  }

  int gi[2][4], irow[2][4];
#pragma unroll
  for (int t2 = 0; t2 < 2; t2++)
#pragma unroll
    for (int r = 0; r < 4; r++) {
      irow[t2][r] = rowBase + w * 32 + t2 * 16 + lg * 4 + r;  // C/D row map
      gi[t2][r] = gb[irow[t2][r]];
    }

  float dP[2][4] = {{0.f, 0.f, 0.f, 0.f}, {0.f, 0.f, 0.f, 0.f}};
  float nP[2][4] = {{0.f, 0.f, 0.f, 0.f}, {0.f, 0.f, 0.f, 0.f}};

  __syncthreads();  // tile 0 ready (compiler emits vmcnt(0) before barrier)

  for (int t = 0; t < NT; t++) {
    const int cur = t & 1;
    if (t + 1 < NT) {  // prefetch next tile into the other buffer
      const char* sn = srcBase + (size_t)(t + 1) * 32768;
      char* ln = (char*)colZ[cur ^ 1] + ldsOff;
#pragma unroll
      for (int i = 0; i < 8; i++)
        gload16(sn + i * 4096, ln + i * 4096);
    }
    const char* bufc = (const char*)colZ[cur];
#pragma unroll
    for (int sub = 0; sub < 4; sub++) {
      f32x4 acc0 = {0.f, 0.f, 0.f, 0.f};
      f32x4 acc1 = {0.f, 0.f, 0.f, 0.f};
      const int brow = sub * 16 + l15;
      const char* bbase = bufc + brow * 512;
      const int bx = (brow & 7) << 4;
#pragma unroll
      for (int kt = 0; kt < 8; kt++) {
        const bf16x8 bfrag = *(const bf16x8*)(bbase + ((lg * 16 + kt * 64) ^ bx));
        acc0 = __builtin_amdgcn_mfma_f32_16x16x32_bf16(afrag[0][kt], bfrag, acc0, 0, 0, 0);
        acc1 = __builtin_amdgcn_mfma_f32_16x16x32_bf16(afrag[1][kt], bfrag, acc1, 0, 0, 0);
      }
      const int jj = t * 64 + sub * 16 + l15;
      const int j = chunkBase + jj;
      const int gj = gb[j];                              // L1-hot broadcast read
      const float bias = (gj & 0x10000) ? NEGB : 0.f;    // mask -> exp() == 0
#pragma unroll
      for (int r = 0; r < 4; r++) {
        float a0 = bias, a1 = bias;
        if (hasDiag) {  // block-uniform branch; only 1/4 of blocks pay this
          if (j == irow[0][r]) a0 = NEGB;
          if (j == irow[1][r]) a1 = NEGB;
        }
        const float e0 = __builtin_exp2f(fmaf(acc0[r], 14.4269504089f, a0));
        const float e1 = __builtin_exp2f(fmaf(acc1[r], 14.4269504089f, a1));
        dP[0][r] += e0;
        dP[1][r] += e1;
        if (gj == gi[0][r]) nP[0][r] += e0;
        if (gj == gi[1][r]) nP[1][r] += e1;
      }
    }
    __syncthreads();  // drains prefetch (late) + protects buffer reuse
  }

  // reduce over the 16-lane column axis; lane l15==0 owns the row
#pragma unroll
  for (int t2 = 0; t2 < 2; t2++)
#pragma unroll
    for (int r = 0; r < 4; r++) {
      float d = dP[t2][r], n = nP[t2][r];
#pragma unroll
      for (int m = 1; m < 16; m <<= 1) {
        d += __shfl_xor(d, m);
        n += __shfl_xor(n, m);
      }
      if (l15 == 0) {
        const int row = rowBase + w * 32 + t2 * 16 + lg * 4 + r;
        const size_t o = ((size_t)blockIdx.y * B_ + b) * N_ + row;  // [chunk][b][row]
        pd[o] = d;
        pn[o] = n;
      }
    }
}

__global__ void finalize_kernel(const float* __restrict__ pd, const float* __restrict__ pn,
                                const int* __restrict__ gm, float* gsum) {
  const int i = blockIdx.x * 256 + threadIdx.x;
  float d = 0.f, n = 0.f;
#pragma unroll
  for (int c = 0; c < NCH; c++) {
    d += pd[(size_t)c * (B_ * N_) + i];
    n += pn[(size_t)c * (B_ * N_) + i];
  }
  float contrib = 0.f, cnt = 0.f;
  if (!(gm[i] & 0x10000) && n > 0.f) {
    contrib = __logf(d) - __logf(n);  // -log(numer/denom)
    cnt = 1.f;
  }
#pragma unroll
  for (int m = 1; m < 64; m <<= 1) {
    contrib += __shfl_xor(contrib, m);
    cnt += __shfl_xor(cnt, m);
  }
  __shared__ float sc[4], sn[4];
  const int w = threadIdx.x >> 6;
  if ((threadIdx.x & 63) == 0) { sc[w] = contrib; sn[w] = cnt; }
  __syncthreads();
  if (threadIdx.x == 0) {
    atomicAdd(&gsum[0], sc[0] + sc[1] + sc[2] + sc[3]);
    atomicAdd(&gsum[1], sn[0] + sn[1] + sn[2] + sn[3]);
  }
}

__global__ void fin_kernel(const float* gsum, float* out) {
  const float s = gsum[0], c = gsum[1];
  out[0] = (c > 0.f) ? s / fmaxf(c, 1.f) : 0.f;
}

extern "C" void kernel_launch(void* const* d_in, const int* in_sizes, int n_in,
                              void* d_out, int out_size, void* d_ws, size_t ws_size,
                              hipStream_t stream) {
  const float* emb = (const float*)d_in[0];
  const int* groups = (const int*)d_in[1];
  const void* mask = d_in[2];
  float* out = (float*)d_out;

  char* ws = (char*)d_ws;
  float* gsum = (float*)ws;
  int* gm = (int*)(ws + 64);
  unsigned short* z = (unsigned short*)(ws + 65600);
  float* pd = (float*)(ws + 8454208);
  float* pn = (float*)(ws + 8716352);

  det_kernel<<<1, 256, 0, stream>>>((const int*)mask, gsum);
  norm_kernel<<<(B_ * N_) / 4, 256, 0, stream>>>(emb, mask, groups, gsum, z, gm);
  main_kernel<<<dim3(N_ / BROWS, NCH, B_), 256, 0, stream>>>(z, gm, pd, pn);
  finalize_kernel<<<(B_ * N_) / 256, 256, 0, stream>>>(pd, pn, gm, gsum);
  fin_kernel<<<1, 1, 0, stream>>>(gsum, out);
}

// Round 4
// 49.096 us; speedup vs baseline: 2.6274x; 1.0188x over previous
//
#include <hip/hip_runtime.h>
#include <hip/hip_bf16.h>

// InfoNCE loss, B=8, N=2048, D=256, T=0.1 — mask-compacted formulation.
// Masked-out rows/cols contribute nothing (exp*0 in reference), so we
// compact to the ~N/2 masked-in indices per batch before the GEMM.
// ws layout (~9.1 MB):
//   [0]       float gsum[16] (0: loss sum, 1: count)
//   [64]      int   done
//   [128]     int   mcnt[B]
//   [192]     int   idx[B][2048]      compacted -> original index
//   [65728]   int   gc[B][2048]       compacted groups (pad = 0x10000)
//   [131264]  ushort zc[B][2048][256] compacted bf16-normalized rows
//   [8519872] float pd[NCH][B][2048]  per-chunk denom partials
//   [8782016] float pn[NCH][B][2048]  per-chunk numer partials

#define B_ 8
#define N_ 2048
#define D_ 256
#define NCH 4     // column-tile chunks (tile t -> chunk t%NCH)
#define BROWS 64  // rows per block = 4 waves x 16 rows
#define NEGB -16384.0f

typedef __attribute__((ext_vector_type(8))) short bf16x8;
typedef __attribute__((ext_vector_type(4))) float f32x4;

__device__ __forceinline__ void gload16(const void* g, void* l) {
  __builtin_amdgcn_global_load_lds(
      (const __attribute__((address_space(1))) void*)g,
      (__attribute__((address_space(3))) void*)l, 16, 0, 0);
}

// One block per batch: detect mask dtype, prefix-scan mask, emit compacted
// index list + compacted groups (+sentinel pad), per-batch count. Block 0
// also zeroes the global accumulators.
__global__ void scan_kernel(const void* __restrict__ maskRaw, const int* __restrict__ groups,
                            int* __restrict__ idx, int* __restrict__ gc,
                            int* __restrict__ mcnt, float* gsum, int* done) {
  const int b = blockIdx.x, tid = threadIdx.x;
  __shared__ int cnt_s;
  __shared__ int warpOff[4];
  if (tid == 0) cnt_s = 0;
  __syncthreads();
  // dtype detect over first 16KB (in-bounds for both bool and int32)
  const int4* p4 = (const int4*)maskRaw;
  int c = 0;
  for (int i = tid; i < 1024; i += 256) {
    const int4 v = p4[i];
    c += ((v.x & 0xFFFFFF00) != 0) + ((v.y & 0xFFFFFF00) != 0) +
         ((v.z & 0xFFFFFF00) != 0) + ((v.w & 0xFFFFFF00) != 0);
  }
  atomicAdd(&cnt_s, c);
  __syncthreads();
  const bool isInt = (cnt_s == 0);  // int32 0/1 values: upper bytes all zero

  unsigned int bits = 0;
  if (isInt) {
    const int* ip = (const int*)maskRaw + b * N_ + tid * 8;
#pragma unroll
    for (int e = 0; e < 8; e++) bits |= (unsigned)(ip[e] != 0) << e;
  } else {
    const unsigned char* bp = (const unsigned char*)maskRaw + b * N_ + tid * 8;
#pragma unroll
    for (int e = 0; e < 8; e++) bits |= (unsigned)(bp[e] != 0) << e;
  }
  const int myc = __popc(bits);
  // inclusive scan within wave, then cross-wave offsets via LDS
  int pre = myc;
#pragma unroll
  for (int s = 1; s < 64; s <<= 1) {
    const int t = __shfl_up(pre, s);
    if ((tid & 63) >= s) pre += t;
  }
  const int w = tid >> 6;
  if ((tid & 63) == 63) warpOff[w] = pre;
  __syncthreads();
  int wbase = 0;
#pragma unroll
  for (int ww = 0; ww < 4; ww++) wbase += (ww < w) ? warpOff[ww] : 0;
  int pos = wbase + pre - myc;  // exclusive prefix
  const int m = warpOff[0] + warpOff[1] + warpOff[2] + warpOff[3];

  const int* gp = groups + b * N_;
#pragma unroll
  for (int e = 0; e < 8; e++) {
    if (bits & (1u << e)) {
      const int i = tid * 8 + e;
      idx[b * N_ + pos] = i;
      gc[b * N_ + pos] = gp[i];
      pos++;
    }
  }
  if (tid == 0) mcnt[b] = m;
  const int mpad = (m + 63) & ~63;
  if (tid < 64 && m + tid < mpad) gc[b * N_ + m + tid] = 0x10000;  // pad sentinel
  if (b == 0 && tid == 0) { gsum[0] = 0.f; gsum[1] = 0.f; *done = 0; }
}

// One wave per compacted row: gather emb[idx[k]], L2-normalize, bf16 -> zc.
// Pad rows [m, mpad) zeroed so staged tiles stay finite.
__global__ void gather_kernel(const float* __restrict__ emb, const int* __restrict__ idx,
                              const int* __restrict__ mcnt, unsigned short* __restrict__ zc) {
  const int w = threadIdx.x >> 6, l = threadIdx.x & 63;
  const int r = blockIdx.x * 4 + w;
  const int b = r >> 11, k = r & (N_ - 1);
  const int m = mcnt[b];
  const int mpad = (m + 63) & ~63;
  if (k >= mpad) return;
  ushort4 o = {0, 0, 0, 0};
  if (k < m) {
    const int i = idx[b * N_ + k];
    const float4 v = *(const float4*)(emb + ((size_t)b * N_ + i) * D_ + l * 4);
    float ss = v.x * v.x + v.y * v.y + v.z * v.z + v.w * v.w;
#pragma unroll
    for (int s = 1; s < 64; s <<= 1) ss += __shfl_xor(ss, s);
    const float inv = 1.f / fmaxf(sqrtf(ss), 1e-12f);
    union { ushort4 u; __hip_bfloat162 h[2]; } p;
    p.h[0] = __float22bfloat162_rn(float2{v.x * inv, v.y * inv});
    p.h[1] = __float22bfloat162_rn(float2{v.z * inv, v.w * inv});
    o = p.u;
  }
  *(ushort4*)(zc + ((size_t)b * N_ + k) * D_ + l * 4) = o;
}

// Block: 4 waves x 16 rows = 64 compacted rows; column tiles t = y, y+NCH,...
// Double-buffered 64-col LDS tiles via global_load_lds (linear LDS dest,
// XOR-pre-swizzled source; reads use the matching XOR). 2-phase prefetch.
__global__ __launch_bounds__(256, 2) void main_kernel(
    const unsigned short* __restrict__ zc, const int* __restrict__ gc,
    const int* __restrict__ mcnt, float* __restrict__ pd, float* __restrict__ pn) {
  __shared__ unsigned short colZ[2][64 * 256];  // 2 x 32 KB
  __shared__ int gjs[2][64];

  const int b = blockIdx.z;
  const int m = mcnt[b];
  const int rowBase = blockIdx.x * BROWS;
  if (rowBase >= m) return;  // no valid rows in this block
  const int ntiles = (m + 63) >> 6;
  const int y = blockIdx.y;
  const int nt = (ntiles - y + NCH - 1) / NCH;  // tiles assigned to this chunk
  if (nt <= 0) return;

  const int tid = threadIdx.x;
  const int w = tid >> 6, l = tid & 63, l15 = l & 15, lg = l >> 4;
  const unsigned short* zb = zc + (size_t)b * N_ * D_;
  const int* gb = gc + b * N_;

  const int srcOff = (tid * 16) ^ (((tid >> 5) & 7) << 4);
  const int ldsOff = tid * 16;

  // prologue: stage tile y
  {
    const char* s0 = (const char*)zb + (size_t)y * 32768 + srcOff;
#pragma unroll
    for (int i = 0; i < 8; i++)
      gload16(s0 + i * 4096, (char*)colZ[0] + i * 4096 + ldsOff);
    if (tid < 64) gjs[0][tid] = gb[y * 64 + tid];
  }

  // A fragment: lane holds row (l&15), k = kt*32 + lg*8 + e
  bf16x8 afrag[8];
  const int arow = rowBase + w * 16 + l15;
#pragma unroll
  for (int kt = 0; kt < 8; kt++)
    afrag[kt] = *(const bf16x8*)(zb + (size_t)arow * D_ + kt * 32 + lg * 8);

  int irow[4], gi[4];
#pragma unroll
  for (int r = 0; r < 4; r++) {
    irow[r] = rowBase + w * 16 + lg * 4 + r;  // C/D row map
    gi[r] = gb[irow[r]];
  }

  float dP[4] = {0.f, 0.f, 0.f, 0.f};
  float nP[4] = {0.f, 0.f, 0.f, 0.f};

  __syncthreads();  // tile 0 ready (vmcnt(0) folded into barrier)

  for (int it = 0; it < nt; it++) {
    const int ct = y + it * NCH;
    const int cur = it & 1;
    if (it + 1 < nt) {  // prefetch next assigned tile
      const int cn = ct + NCH;
      const char* sn = (const char*)zb + (size_t)cn * 32768 + srcOff;
      char* ln = (char*)colZ[cur ^ 1] + ldsOff;
#pragma unroll
      for (int i = 0; i < 8; i++) gload16(sn + i * 4096, ln + i * 4096);
      if (tid < 64) gjs[cur ^ 1][tid] = gb[cn * 64 + tid];
    }
    const bool diagT = (ct == (int)blockIdx.x);  // block-uniform
    const char* bufc = (const char*)colZ[cur];
#pragma unroll
    for (int sub = 0; sub < 4; sub++) {
      f32x4 acc = {0.f, 0.f, 0.f, 0.f};
      const int brow = sub * 16 + l15;
      const char* bbase = bufc + brow * 512;
      const int bx = (brow & 7) << 4;
#pragma unroll
      for (int kt = 0; kt < 8; kt++) {
        const bf16x8 bfrag = *(const bf16x8*)(bbase + ((lg * 16 + kt * 64) ^ bx));
        acc = __builtin_amdgcn_mfma_f32_16x16x32_bf16(afrag[kt], bfrag, acc, 0, 0, 0);
      }
      const int j = ct * 64 + sub * 16 + l15;
      const int gj = gjs[cur][sub * 16 + l15];
      const float bias = (gj & 0x10000) ? NEGB : 0.f;  // pad col -> exp == 0
#pragma unroll
      for (int r = 0; r < 4; r++) {
        float a0 = bias;
        if (diagT && j == irow[r]) a0 = NEGB;  // exclude diagonal
        const float e0 = __builtin_exp2f(fmaf(acc[r], 14.4269504089f, a0));
        dP[r] += e0;
        if (gj == gi[r]) nP[r] += e0;
      }
    }
    __syncthreads();  // drains prefetch + protects buffer reuse
  }

  // reduce over the 16-lane column axis; lane l15==0 owns the row
#pragma unroll
  for (int r = 0; r < 4; r++) {
    float d = dP[r], n = nP[r];
#pragma unroll
    for (int mm = 1; mm < 16; mm <<= 1) {
      d += __shfl_xor(d, mm);
      n += __shfl_xor(n, mm);
    }
    if (l15 == 0) {
      const int row = rowBase + w * 16 + lg * 4 + r;
      const size_t o = ((size_t)y * B_ + b) * N_ + row;  // [chunk][b][row]
      pd[o] = d;
      pn[o] = n;
    }
  }
}

// Per compacted row: loss contribution; fused final division via done-counter.
__global__ void finalize_kernel(const float* __restrict__ pd, const float* __restrict__ pn,
                                const int* __restrict__ mcnt, float* gsum, int* done,
                                float* out) {
  const int g = blockIdx.x * 256 + threadIdx.x;
  const int b = g >> 11, k = g & (N_ - 1);
  const int m = mcnt[b];
  float contrib = 0.f, cnt = 0.f;
  if (k < m) {
    const int nch = min(NCH, (m + 63) >> 6);
    float d = 0.f, n = 0.f;
    for (int c = 0; c < nch; c++) {
      d += pd[((size_t)c * B_ + b) * N_ + k];
      n += pn[((size_t)c * B_ + b) * N_ + k];
    }
    if (n > 0.f) {
      contrib = __logf(d) - __logf(n);  // -log(numer/denom)
      cnt = 1.f;
    }
  }
#pragma unroll
  for (int s = 1; s < 64; s <<= 1) {
    contrib += __shfl_xor(contrib, s);
    cnt += __shfl_xor(cnt, s);
  }
  __shared__ float sc[4], sn[4];
  __shared__ bool isLast;
  const int w = threadIdx.x >> 6;
  if ((threadIdx.x & 63) == 0) { sc[w] = contrib; sn[w] = cnt; }
  __syncthreads();
  if (threadIdx.x == 0) {
    atomicAdd(&gsum[0], sc[0] + sc[1] + sc[2] + sc[3]);
    atomicAdd(&gsum[1], sn[0] + sn[1] + sn[2] + sn[3]);
    __threadfence();
    isLast = (atomicAdd(done, 1) == (int)gridDim.x - 1);
  }
  __syncthreads();
  if (isLast && threadIdx.x == 0) {
    const float s = atomicAdd(&gsum[0], 0.f);  // coherent read
    const float c = atomicAdd(&gsum[1], 0.f);
    out[0] = (c > 0.f) ? s / fmaxf(c, 1.f) : 0.f;
  }
}

extern "C" void kernel_launch(void* const* d_in, const int* in_sizes, int n_in,
                              void* d_out, int out_size, void* d_ws, size_t ws_size,
                              hipStream_t stream) {
  const float* emb = (const float*)d_in[0];
  const int* groups = (const int*)d_in[1];
  const void* mask = d_in[2];
  float* out = (float*)d_out;

  char* ws = (char*)d_ws;
  float* gsum = (float*)ws;
  int* done = (int*)(ws + 64);
  int* mcnt = (int*)(ws + 128);
  int* idx = (int*)(ws + 192);
  int* gc = (int*)(ws + 65728);
  unsigned short* zc = (unsigned short*)(ws + 131264);
  float* pd = (float*)(ws + 8519872);
  float* pn = (float*)(ws + 8782016);

  scan_kernel<<<B_, 256, 0, stream>>>(mask, groups, idx, gc, mcnt, gsum, done);
  gather_kernel<<<(B_ * N_) / 4, 256, 0, stream>>>(emb, idx, mcnt, zc);
  main_kernel<<<dim3(N_ / BROWS, NCH, B_), 256, 0, stream>>>(zc, gc, mcnt, pd, pn);
  finalize_kernel<<<(B_ * N_) / 256, 256, 0, stream>>>(pd, pn, mcnt, gsum, done, out);
}